// Round 9
// baseline (53.047 us; speedup 1.0000x reference)
//
#include <hip/hip_runtime.h>
#include <math.h>

#define TEMP 0.07f
#define NTOK 1024
#define CAP 64    // max group size; data Poisson(~8), max ~25 -> safe margin
#define SUBT 64   // sub-ticket fan-in (keeps same-address atomic serialization ~0.5us)

// D2: fused prep. Wave handles 4 rows (16 lanes x float4): inverse L2 norm via
// 4-shfl butterfly + direct bucket insert (global atomic cursor; order within a
// group is irrelevant to the sum-of-exps).
__global__ __launch_bounds__(256) void prep_kernel(const float* __restrict__ x,
        const int* __restrict__ tok, float* __restrict__ invn,
        int* __restrict__ cursor, int* __restrict__ bucket, int n) {
    const int lane = threadIdx.x & 63;
    const int w = blockIdx.x * 4 + (threadIdx.x >> 6);
    const int sub = lane & 15, grp = lane >> 4;
    const int row = w * 4 + grp;
    if (row >= n) return;
    float4 v = *(const float4*)&x[row * 64 + sub * 4];
    float s = v.x * v.x + v.y * v.y + v.z * v.z + v.w * v.w;
    s += __shfl_xor(s, 1, 64);
    s += __shfl_xor(s, 2, 64);
    s += __shfl_xor(s, 4, 64);
    s += __shfl_xor(s, 8, 64);
    if (sub == 0) {
        invn[row] = 1.0f / fmaxf(sqrtf(s), 1e-12f);
        int g = tok[row];
        int slot = atomicAdd(&cursor[g], 1);
        if (slot < CAP) bucket[g * CAP + slot] = row;
    }
}

// D3: wave per anchor (4 waves/block) + fused finalize via 2-level ticket.
// Hot loop identical to round-8 lse (proven): bucket-direct members, 16-lane
// float4 dot, 4 shared shfl stages, precomputed invn.
__global__ __launch_bounds__(256) void lse_fin_kernel(const float* __restrict__ x,
        const int* __restrict__ tok, const float* __restrict__ invn,
        const int* __restrict__ cursor, const int* __restrict__ bucket,
        unsigned long long* __restrict__ blk_loss, int* __restrict__ blk_m,
        unsigned* __restrict__ subt, unsigned* __restrict__ root,
        float* __restrict__ out, int n) {
    const int lane = threadIdx.x & 63;
    const int wid  = threadIdx.x >> 6;
    const int i = blockIdx.x * 4 + wid;
    const int nblk = gridDim.x;

    double pa = 0.0;
    int m = 0;
    if (i < n) {
        int g = tok[i];
        int cnt = min(cursor[g], CAP);
        if (cnt >= 2) {
            const int sub = lane & 15, grp = lane >> 4;
            float4 zi = *(const float4*)&x[i * 64 + sub * 4];
            float sc = invn[i] * (1.0f / TEMP);   // fold invn_i and 1/T
            zi.x *= sc; zi.y *= sc; zi.z *= sc; zi.w *= sc;
            const int* bk = &bucket[g * CAP];
            float S = 0.0f;
            for (int m0 = 0; m0 < cnt; m0 += 4) {
                int mm = m0 + grp;
                bool act = (mm < cnt);
                int j = act ? bk[mm] : 0;                   // j=0: safe dummy
                act = act && (j != i);                      // exclude self
                float4 zj = *(const float4*)&x[j * 64 + sub * 4];
                float iv = invn[j];                         // indep of row load
                float d = zi.x * zj.x + zi.y * zj.y + zi.z * zj.z + zi.w * zj.w;
                d += __shfl_xor(d, 1, 64);
                d += __shfl_xor(d, 2, 64);
                d += __shfl_xor(d, 4, 64);
                d += __shfl_xor(d, 8, 64);                  // row-of-16 reduce
                // logit bounded by 1/T=14.3 -> f32 exp safe w/o max-sub
                float e = act ? __expf(-d * iv) : 0.0f;
                S += (sub == 0) ? e : 0.0f;                 // 1 lane per member
            }
            S += __shfl_xor(S, 16, 64);
            S += __shfl_xor(S, 32, 64);     // lane0 = lanes {0,16,32,48}
            pa = (double)(-__logf(S));
            m = cnt - 1;
        }
    }

    // block partial (4 waves), then 2-level ticket
    __shared__ double lred[4];
    __shared__ int    mred[4];
    __shared__ bool   lastFlag;
    if (lane == 0) { lred[wid] = pa; mred[wid] = m; }
    __syncthreads();
    if (threadIdx.x == 0) {
        double ls = lred[0] + lred[1] + lred[2] + lred[3];
        int    ms = mred[0] + mred[1] + mred[2] + mred[3];
        // coherence-point writes (visible cross-XCD), then fence, then ticket
        atomicExch(&blk_loss[blockIdx.x], (unsigned long long)__double_as_longlong(ls));
        atomicExch(&blk_m[blockIdx.x], ms);
        __threadfence();
        int sg = blockIdx.x & (SUBT - 1);
        int rem = nblk & (SUBT - 1);
        int quota = nblk / SUBT + (sg < rem ? 1 : 0);       // blocks in subgroup
        bool last = false;
        unsigned v = atomicAdd(&subt[sg], 1u);
        if ((int)v == quota - 1) {                          // subgroup winner
            int nsub = (nblk < SUBT) ? nblk : SUBT;
            unsigned r = atomicAdd(root, 1u);
            last = ((int)r == nsub - 1);                    // global last
        }
        lastFlag = last;
    }
    __syncthreads();
    if (!lastFlag) return;

    // last block: coherent re-read of all partials, fixed-order tree reduce
    double ls = 0.0;
    long long ps = 0;
    for (int k = threadIdx.x; k < nblk; k += 256) {
        ls += __longlong_as_double((long long)atomicAdd(&blk_loss[k], 0ull));
        ps += (long long)atomicAdd(&blk_m[k], 0);
    }
    __shared__ double    fl[256];
    __shared__ long long fp[256];
    fl[threadIdx.x] = ls;
    fp[threadIdx.x] = ps;
    __syncthreads();
    for (int off = 128; off; off >>= 1) {
        if (threadIdx.x < off) {
            fl[threadIdx.x] += fl[threadIdx.x + off];
            fp[threadIdx.x] += fp[threadIdx.x + off];
        }
        __syncthreads();
    }
    if (threadIdx.x == 0)
        out[0] = (fp[0] > 0) ? (float)(fl[0] / (double)fp[0]) : 0.0f;
}

extern "C" void kernel_launch(void* const* d_in, const int* in_sizes, int n_in,
                              void* d_out, int out_size, void* d_ws, size_t ws_size,
                              hipStream_t stream) {
    const float* x = (const float*)d_in[0];
    const int* tok = (const int*)d_in[1];
    int n = in_sizes[1];  // 8192 rows, D = 64
    int nblk = (n + 3) / 4;

    char* ws = (char*)d_ws;
    size_t o = 0;
    // zeroed region: cursor + sub-tickets + root (one memset)
    int* cursor = (int*)(ws + o);           o += NTOK * 4;
    unsigned* subt = (unsigned*)(ws + o);   o += SUBT * 4;
    unsigned* root = (unsigned*)(ws + o);   o += 256;       // pad to 256B align
    size_t zero_len = o;
    float* invn = (float*)(ws + o);         o += ((size_t)n * 4 + 255) & ~255UL;
    int* bucket = (int*)(ws + o);           o += (size_t)NTOK * CAP * 4;
    unsigned long long* blk_loss = (unsigned long long*)(ws + o); o += (size_t)nblk * 8;
    int* blk_m = (int*)(ws + o);
    // blk_loss/blk_m: slot k written by block k before any ticket -> read-safe

    hipMemsetAsync(ws, 0, zero_len, stream);
    prep_kernel<<<(n + 15) / 16, 256, 0, stream>>>(x, tok, invn, cursor, bucket, n);
    lse_fin_kernel<<<nblk, 256, 0, stream>>>(x, tok, invn, cursor, bucket,
                                             blk_loss, blk_m, subt, root,
                                             (float*)d_out, n);
}

// Round 10
// 21.709 us; speedup vs baseline: 2.4436x; 2.4436x over previous
//
#include <hip/hip_runtime.h>
#include <math.h>

#define TEMP 0.07f
#define NTOK 1024
#define CAP 64   // max group size; data Poisson(~8), max ~25 -> safe margin

// K1: fused prep. Wave handles 8 rows (8 lanes x 2 float4 each): inverse L2
// norm via 3-shfl butterfly + direct bucket insert (global atomic cursor;
// within-group order is irrelevant to the sum-of-exps).
__global__ __launch_bounds__(256) void prep_kernel(const float* __restrict__ x,
        const int* __restrict__ tok, float* __restrict__ invn,
        int* __restrict__ cursor, int* __restrict__ bucket, int n) {
    const int lane = threadIdx.x & 63;
    const int w = blockIdx.x * 4 + (threadIdx.x >> 6);
    const int sub = lane & 7, mem = lane >> 3;
    const int row = w * 8 + mem;
    if (row >= n) return;
    const float4* xr = (const float4*)&x[row * 64 + sub * 8];
    float4 a = xr[0], b = xr[1];
    float s = a.x * a.x + a.y * a.y + a.z * a.z + a.w * a.w
            + b.x * b.x + b.y * b.y + b.z * b.z + b.w * b.w;
    s += __shfl_xor(s, 1, 64);
    s += __shfl_xor(s, 2, 64);
    s += __shfl_xor(s, 4, 64);                       // row-of-8 reduce
    if (sub == 0) {
        invn[row] = 1.0f / fmaxf(sqrtf(s), 1e-12f);
        int g = tok[row];
        int slot = atomicAdd(&cursor[g], 1);
        if (slot < CAP) bucket[g * CAP + slot] = row;
    }
}

// K2: wave per anchor (4 waves/block). 8 members per iteration: 8 lanes x
// 2 float4 per member, 3 shared shfl stages -> typical group (~8) completes
// in ONE iteration of the hot loop. Precomputed invn (round-7 lesson).
__global__ __launch_bounds__(256) void lse_kernel(const float* __restrict__ x,
        const int* __restrict__ tok, const float* __restrict__ invn,
        const int* __restrict__ cursor, const int* __restrict__ bucket,
        float* __restrict__ per_anchor, int n) {
    const int lane = threadIdx.x & 63;
    const int i = blockIdx.x * 4 + (threadIdx.x >> 6);
    if (i >= n) return;
    const int g = tok[i];
    const int cnt = min(cursor[g], CAP);
    if (cnt < 2) {                        // no partner: contributes 0
        if (lane == 0) per_anchor[i] = 0.0f;
        return;
    }
    const int sub = lane & 7, mem = lane >> 3;
    const float4* zr = (const float4*)&x[i * 64 + sub * 8];
    float4 za = zr[0], zb = zr[1];
    float sc = invn[i] * (1.0f / TEMP);   // fold invn_i and 1/T into anchor
    za.x *= sc; za.y *= sc; za.z *= sc; za.w *= sc;
    zb.x *= sc; zb.y *= sc; zb.z *= sc; zb.w *= sc;
    const int* bk = &bucket[g * CAP];
    float S = 0.0f;
    for (int m0 = 0; m0 < cnt; m0 += 8) {
        int mm = m0 + mem;
        bool act = (mm < cnt);
        int j = act ? bk[mm] : 0;                    // j=0: safe dummy row
        act = act && (j != i);                       // exclude self
        const float4* xr = (const float4*)&x[j * 64 + sub * 8];
        float4 a = xr[0], b = xr[1];
        float iv = invn[j];                          // indep of row load
        float d = za.x * a.x + za.y * a.y + za.z * a.z + za.w * a.w
                + zb.x * b.x + zb.y * b.y + zb.z * b.z + zb.w * b.w;
        d += __shfl_xor(d, 1, 64);
        d += __shfl_xor(d, 2, 64);
        d += __shfl_xor(d, 4, 64);                   // row-of-8 reduce
        // logit bounded by 1/T = 14.3 -> f32 exp safe without max-sub
        float e = act ? __expf(-d * iv) : 0.0f;
        S += (sub == 0) ? e : 0.0f;                  // 1 lane per member
    }
    S += __shfl_xor(S, 8, 64);
    S += __shfl_xor(S, 16, 64);
    S += __shfl_xor(S, 32, 64);                      // lanes {0,8,..,56}
    if (lane == 0) per_anchor[i] = -__logf(S);
}

// K3: deterministic reduction (wave shfl + single barrier);
// num_pairs = sum c*(c-1) from cursors.
__global__ __launch_bounds__(1024) void finalize_kernel(
        const float* __restrict__ per_anchor, const int* __restrict__ cursor,
        float* __restrict__ out, int n) {
    int t = threadIdx.x;
    double s = 0.0;
    const float4* pa4 = (const float4*)per_anchor;
    int n4 = n >> 2;
    for (int k = t; k < n4; k += 1024) {
        float4 v = pa4[k];
        s += (double)v.x + (double)v.y + (double)v.z + (double)v.w;
    }
    for (int k = (n4 << 2) + t; k < n; k += 1024) s += (double)per_anchor[k];
    long long c = cursor[t];          // blockDim == NTOK
    long long p = c * (c - 1);
    #pragma unroll
    for (int o = 32; o; o >>= 1) {    // fixed xor pattern -> deterministic
        s += __shfl_xor(s, o, 64);
        p += __shfl_xor(p, o, 64);
    }
    __shared__ double    ls[16];
    __shared__ long long lp[16];
    int wid = t >> 6, lane = t & 63;
    if (lane == 0) { ls[wid] = s; lp[wid] = p; }
    __syncthreads();
    if (wid == 0) {
        double fs = (lane < 16) ? ls[lane] : 0.0;
        long long fp = (lane < 16) ? lp[lane] : 0;
        #pragma unroll
        for (int o = 8; o; o >>= 1) {
            fs += __shfl_xor(fs, o, 64);
            fp += __shfl_xor(fp, o, 64);
        }
        if (lane == 0) out[0] = (fp > 0) ? (float)(fs / (double)fp) : 0.0f;
    }
}

extern "C" void kernel_launch(void* const* d_in, const int* in_sizes, int n_in,
                              void* d_out, int out_size, void* d_ws, size_t ws_size,
                              hipStream_t stream) {
    const float* x = (const float*)d_in[0];
    const int* tok = (const int*)d_in[1];
    int n = in_sizes[1];  // 8192 rows, D = 64

    char* ws = (char*)d_ws;
    size_t o = 0;
    int* cursor = (int*)(ws + o);         o += NTOK * 4;
    float* invn = (float*)(ws + o);       o += ((size_t)n * 4 + 255) & ~255UL;
    int* bucket = (int*)(ws + o);         o += (size_t)NTOK * CAP * 4;
    float* per_anchor = (float*)(ws + o);
    // cursor zeroed each call below; all other words written before read

    hipMemsetAsync(cursor, 0, NTOK * 4, stream);
    prep_kernel<<<(n + 31) / 32, 256, 0, stream>>>(x, tok, invn, cursor, bucket, n);
    lse_kernel<<<(n + 3) / 4, 256, 0, stream>>>(x, tok, invn, cursor, bucket,
                                                per_anchor, n);
    finalize_kernel<<<1, NTOK, 0, stream>>>(per_anchor, cursor, (float*)d_out, n);
}

// Round 11
// 19.023 us; speedup vs baseline: 2.7886x; 1.1412x over previous
//
#include <hip/hip_runtime.h>
#include <math.h>

#define TEMP 0.07f
#define NTOK 1024
#define CAP 64   // max group size; data Poisson(~8), max ~25 -> safe margin

// K1: single block, 1024 threads. Bucket build with LDS cursors (zeroed in
// LDS -> no global memset dispatch). Within-group order is atomic-order,
// which is irrelevant to the sum-of-exps (f32 jitter << threshold).
__global__ __launch_bounds__(1024) void bucket_kernel(const int* __restrict__ tok,
        int* __restrict__ cursor, int* __restrict__ bucket, int n) {
    __shared__ int cur[NTOK];
    int t = threadIdx.x;
    cur[t] = 0;
    __syncthreads();
    const int4* tok4 = (const int4*)tok;
    int n4 = n >> 2;
    for (int k = t; k < n4; k += 1024) {
        int4 v = tok4[k];
        int base = k << 2;
        int s0 = atomicAdd(&cur[v.x], 1); if (s0 < CAP) bucket[v.x * CAP + s0] = base;
        int s1 = atomicAdd(&cur[v.y], 1); if (s1 < CAP) bucket[v.y * CAP + s1] = base + 1;
        int s2 = atomicAdd(&cur[v.z], 1); if (s2 < CAP) bucket[v.z * CAP + s2] = base + 2;
        int s3 = atomicAdd(&cur[v.w], 1); if (s3 < CAP) bucket[v.w * CAP + s3] = base + 3;
    }
    for (int i = (n4 << 2) + t; i < n; i += 1024) {
        int g = tok[i];
        int s = atomicAdd(&cur[g], 1);
        if (s < CAP) bucket[g * CAP + s] = i;
    }
    __syncthreads();
    cursor[t] = cur[t];
}

// K2: wave per anchor (4 waves/block). 8 members/iteration (8 lanes x 2
// float4 each). Member norms fused into the dot butterfly: q reduces in the
// SAME 3 shfl stages as d (independent -> ILP-paired, chain depth unchanged).
// No invn array, no prep kernel.
__global__ __launch_bounds__(256) void lse_kernel(const float* __restrict__ x,
        const int* __restrict__ tok, const int* __restrict__ cursor,
        const int* __restrict__ bucket, float* __restrict__ per_anchor, int n) {
    const int lane = threadIdx.x & 63;
    const int i = blockIdx.x * 4 + (threadIdx.x >> 6);
    if (i >= n) return;
    const int g = tok[i];
    const int cnt = min(cursor[g], CAP);
    if (cnt < 2) {                        // no partner: contributes 0
        if (lane == 0) per_anchor[i] = 0.0f;
        return;
    }
    const int sub = lane & 7, mem = lane >> 3;
    const float4* zr = (const float4*)&x[i * 64 + sub * 8];
    float4 za = zr[0], zb = zr[1];
    float qi = za.x * za.x + za.y * za.y + za.z * za.z + za.w * za.w
             + zb.x * zb.x + zb.y * zb.y + zb.z * zb.z + zb.w * zb.w;
    qi += __shfl_xor(qi, 1, 64);
    qi += __shfl_xor(qi, 2, 64);
    qi += __shfl_xor(qi, 4, 64);                     // anchor |x_i|^2
    float sc = (1.0f / TEMP) / fmaxf(sqrtf(qi), 1e-12f);
    za.x *= sc; za.y *= sc; za.z *= sc; za.w *= sc;  // fold invn_i and 1/T
    zb.x *= sc; zb.y *= sc; zb.z *= sc; zb.w *= sc;
    const int* bk = &bucket[g * CAP];
    float S = 0.0f;
    for (int m0 = 0; m0 < cnt; m0 += 8) {
        int mm = m0 + mem;
        bool act = (mm < cnt);
        int j = act ? bk[mm] : 0;                    // j=0: safe dummy row
        act = act && (j != i);                       // exclude self
        const float4* xr = (const float4*)&x[j * 64 + sub * 8];
        float4 a = xr[0], b = xr[1];
        float d = za.x * a.x + za.y * a.y + za.z * a.z + za.w * a.w
                + zb.x * b.x + zb.y * b.y + zb.z * b.z + zb.w * b.w;
        float q = a.x * a.x + a.y * a.y + a.z * a.z + a.w * a.w
                + b.x * b.x + b.y * b.y + b.z * b.z + b.w * b.w;
        d += __shfl_xor(d, 1, 64); q += __shfl_xor(q, 1, 64);
        d += __shfl_xor(d, 2, 64); q += __shfl_xor(q, 2, 64);
        d += __shfl_xor(d, 4, 64); q += __shfl_xor(q, 4, 64);  // row-of-8
        float iv = 1.0f / fmaxf(sqrtf(q), 1e-12f);
        // logit bounded by 1/T = 14.3 -> f32 exp safe without max-sub
        float e = act ? __expf(-d * iv) : 0.0f;
        S += (sub == 0) ? e : 0.0f;                  // 1 lane per member
    }
    S += __shfl_xor(S, 8, 64);
    S += __shfl_xor(S, 16, 64);
    S += __shfl_xor(S, 32, 64);                      // lanes {0,8,..,56}
    if (lane == 0) per_anchor[i] = -__logf(S);
}

// K3: deterministic reduction (wave shfl + single barrier);
// num_pairs = sum c*(c-1) from cursors.
__global__ __launch_bounds__(1024) void finalize_kernel(
        const float* __restrict__ per_anchor, const int* __restrict__ cursor,
        float* __restrict__ out, int n) {
    int t = threadIdx.x;
    double s = 0.0;
    const float4* pa4 = (const float4*)per_anchor;
    int n4 = n >> 2;
    for (int k = t; k < n4; k += 1024) {
        float4 v = pa4[k];
        s += (double)v.x + (double)v.y + (double)v.z + (double)v.w;
    }
    for (int k = (n4 << 2) + t; k < n; k += 1024) s += (double)per_anchor[k];
    long long c = cursor[t];          // blockDim == NTOK
    long long p = c * (c - 1);
    #pragma unroll
    for (int o = 32; o; o >>= 1) {    // fixed xor pattern -> deterministic
        s += __shfl_xor(s, o, 64);
        p += __shfl_xor(p, o, 64);
    }
    __shared__ double    ls[16];
    __shared__ long long lp[16];
    int wid = t >> 6, lane = t & 63;
    if (lane == 0) { ls[wid] = s; lp[wid] = p; }
    __syncthreads();
    if (wid == 0) {
        double fs = (lane < 16) ? ls[lane] : 0.0;
        long long fp = (lane < 16) ? lp[lane] : 0;
        #pragma unroll
        for (int o = 8; o; o >>= 1) {
            fs += __shfl_xor(fs, o, 64);
            fp += __shfl_xor(fp, o, 64);
        }
        if (lane == 0) out[0] = (fp > 0) ? (float)(fs / (double)fp) : 0.0f;
    }
}

extern "C" void kernel_launch(void* const* d_in, const int* in_sizes, int n_in,
                              void* d_out, int out_size, void* d_ws, size_t ws_size,
                              hipStream_t stream) {
    const float* x = (const float*)d_in[0];
    const int* tok = (const int*)d_in[1];
    int n = in_sizes[1];  // 8192 rows, D = 64

    char* ws = (char*)d_ws;
    size_t o = 0;
    int* cursor = (int*)(ws + o);         o += NTOK * 4;
    int* bucket = (int*)(ws + o);         o += (size_t)NTOK * CAP * 4;
    float* per_anchor = (float*)(ws + o);
    // every word written before read; LDS cursors -> no memset dispatch

    bucket_kernel<<<1, 1024, 0, stream>>>(tok, cursor, bucket, n);
    lse_kernel<<<(n + 3) / 4, 256, 0, stream>>>(x, tok, cursor, bucket,
                                                per_anchor, n);
    finalize_kernel<<<1, NTOK, 0, stream>>>(per_anchor, cursor, (float*)d_out, n);
}

// Round 12
// 18.124 us; speedup vs baseline: 2.9268x; 1.0495x over previous
//
#include <hip/hip_runtime.h>
#include <math.h>

#define TEMP 0.07f
#define NTOK 1024
#define MAXN 8192   // LDS fast path bound (harness shape: n = 8192)

// K1: single block, 1024 threads. LDS histogram -> 2-barrier hierarchical
// wave scan -> LDS scatter -> COALESCED CSR write (order/offsets/counts).
// No global memset, no scattered stores. Within-group order is LDS-atomic
// order; the sum-of-exps is order-independent (f32 jitter << threshold).
__global__ __launch_bounds__(1024) void csr_kernel(const int* __restrict__ tok,
        int* __restrict__ offsets, int* __restrict__ counts,
        int* __restrict__ order, int n) {
    __shared__ int cur[NTOK];       // hist, then scatter cursors
    __shared__ int order_l[MAXN];   // 32 KB staging for coalesced write-out
    __shared__ int wsum[16];
    const int t = threadIdx.x;
    const int lane = t & 63, wid = t >> 6;
    cur[t] = 0;
    __syncthreads();
    const int4* tok4 = (const int4*)tok;
    const int n4 = n >> 2;
    for (int k = t; k < n4; k += 1024) {
        int4 v = tok4[k];
        atomicAdd(&cur[v.x], 1); atomicAdd(&cur[v.y], 1);
        atomicAdd(&cur[v.z], 1); atomicAdd(&cur[v.w], 1);
    }
    for (int i = (n4 << 2) + t; i < n; i += 1024) atomicAdd(&cur[tok[i]], 1);
    __syncthreads();
    const int c = cur[t];
    // wave-level inclusive scan (6 shfl steps)
    int s = c;
    #pragma unroll
    for (int o = 1; o < 64; o <<= 1) {
        int v = __shfl_up(s, o, 64);
        if (lane >= o) s += v;
    }
    if (lane == 63) wsum[wid] = s;
    __syncthreads();
    if (wid == 0) {                 // scan the 16 wave sums (4 steps)
        int ws = (lane < 16) ? wsum[lane] : 0;
        #pragma unroll
        for (int o = 1; o < 16; o <<= 1) {
            int v = __shfl_up(ws, o, 64);
            if (lane >= o) ws += v;
        }
        if (lane < 16) wsum[lane] = ws;
    }
    __syncthreads();
    const int excl = s - c + (wid > 0 ? wsum[wid - 1] : 0);  // exclusive scan
    offsets[t] = excl;
    counts[t] = c;
    __syncthreads();
    cur[t] = excl;                  // reuse as scatter cursors
    __syncthreads();
    if (n <= MAXN) {
        for (int i = t; i < n; i += 1024) {
            int pos = atomicAdd(&cur[tok[i]], 1);
            order_l[pos] = i;       // LDS scatter (cheap)
        }
        __syncthreads();
        int4* order4 = (int4*)order;
        const int4* ol4 = (const int4*)order_l;
        for (int k = t; k < n4; k += 1024) order4[k] = ol4[k];  // coalesced
        for (int i = (n4 << 2) + t; i < n; i += 1024) order[i] = order_l[i];
    } else {                        // generic fallback: direct global scatter
        for (int i = t; i < n; i += 1024) {
            int pos = atomicAdd(&cur[tok[i]], 1);
            order[pos] = i;
        }
    }
}

// K2: wave per anchor (4 waves/block). 8 members/iteration (8 lanes x 2
// float4 each); member norm fused into the dot butterfly (q rides the same
// 3 shfl stages as d -> chain depth unchanged). Group list is a CONTIGUOUS
// run of order[] (adjacent groups share cache lines).
__global__ __launch_bounds__(256) void lse_kernel(const float* __restrict__ x,
        const int* __restrict__ tok, const int* __restrict__ offsets,
        const int* __restrict__ counts, const int* __restrict__ order,
        float* __restrict__ per_anchor, int n) {
    const int lane = threadIdx.x & 63;
    const int i = blockIdx.x * 4 + (threadIdx.x >> 6);
    if (i >= n) return;
    const int g = tok[i];
    const int cnt = counts[g];
    if (cnt < 2) {                        // no partner: contributes 0
        if (lane == 0) per_anchor[i] = 0.0f;
        return;
    }
    const int sub = lane & 7, mem = lane >> 3;
    const float4* zr = (const float4*)&x[i * 64 + sub * 8];
    float4 za = zr[0], zb = zr[1];
    float qi = za.x * za.x + za.y * za.y + za.z * za.z + za.w * za.w
             + zb.x * zb.x + zb.y * zb.y + zb.z * zb.z + zb.w * zb.w;
    qi += __shfl_xor(qi, 1, 64);
    qi += __shfl_xor(qi, 2, 64);
    qi += __shfl_xor(qi, 4, 64);                     // anchor |x_i|^2
    float sc = (1.0f / TEMP) / fmaxf(sqrtf(qi), 1e-12f);
    za.x *= sc; za.y *= sc; za.z *= sc; za.w *= sc;  // fold invn_i and 1/T
    zb.x *= sc; zb.y *= sc; zb.z *= sc; zb.w *= sc;
    const int* bk = &order[offsets[g]];
    float S = 0.0f;
    for (int m0 = 0; m0 < cnt; m0 += 8) {
        int mm = m0 + mem;
        bool act = (mm < cnt);
        int j = act ? bk[act ? mm : 0] : 0;          // safe dummy
        act = act && (j != i);                       // exclude self
        const float4* xr = (const float4*)&x[j * 64 + sub * 8];
        float4 a = xr[0], b = xr[1];
        float d = za.x * a.x + za.y * a.y + za.z * a.z + za.w * a.w
                + zb.x * b.x + zb.y * b.y + zb.z * b.z + zb.w * b.w;
        float q = a.x * a.x + a.y * a.y + a.z * a.z + a.w * a.w
                + b.x * b.x + b.y * b.y + b.z * b.z + b.w * b.w;
        d += __shfl_xor(d, 1, 64); q += __shfl_xor(q, 1, 64);
        d += __shfl_xor(d, 2, 64); q += __shfl_xor(q, 2, 64);
        d += __shfl_xor(d, 4, 64); q += __shfl_xor(q, 4, 64);  // row-of-8
        float iv = 1.0f / fmaxf(sqrtf(q), 1e-12f);
        // logit bounded by 1/T = 14.3 -> f32 exp safe without max-sub
        float e = act ? __expf(-d * iv) : 0.0f;
        S += (sub == 0) ? e : 0.0f;                  // 1 lane per member
    }
    S += __shfl_xor(S, 8, 64);
    S += __shfl_xor(S, 16, 64);
    S += __shfl_xor(S, 32, 64);                      // lanes {0,8,..,56}
    if (lane == 0) per_anchor[i] = -__logf(S);
}

// K3: deterministic reduction (wave shfl + single barrier);
// num_pairs = sum c*(c-1) from counts.
__global__ __launch_bounds__(1024) void finalize_kernel(
        const float* __restrict__ per_anchor, const int* __restrict__ counts,
        float* __restrict__ out, int n) {
    int t = threadIdx.x;
    double s = 0.0;
    const float4* pa4 = (const float4*)per_anchor;
    int n4 = n >> 2;
    for (int k = t; k < n4; k += 1024) {
        float4 v = pa4[k];
        s += (double)v.x + (double)v.y + (double)v.z + (double)v.w;
    }
    for (int k = (n4 << 2) + t; k < n; k += 1024) s += (double)per_anchor[k];
    long long c = counts[t];          // blockDim == NTOK
    long long p = c * (c - 1);
    #pragma unroll
    for (int o = 32; o; o >>= 1) {    // fixed xor pattern -> deterministic
        s += __shfl_xor(s, o, 64);
        p += __shfl_xor(p, o, 64);
    }
    __shared__ double    ls[16];
    __shared__ long long lp[16];
    int wid = t >> 6, lane = t & 63;
    if (lane == 0) { ls[wid] = s; lp[wid] = p; }
    __syncthreads();
    if (wid == 0) {
        double fs = (lane < 16) ? ls[lane] : 0.0;
        long long fp = (lane < 16) ? lp[lane] : 0;
        #pragma unroll
        for (int o = 8; o; o >>= 1) {
            fs += __shfl_xor(fs, o, 64);
            fp += __shfl_xor(fp, o, 64);
        }
        if (lane == 0) out[0] = (fp > 0) ? (float)(fs / (double)fp) : 0.0f;
    }
}

extern "C" void kernel_launch(void* const* d_in, const int* in_sizes, int n_in,
                              void* d_out, int out_size, void* d_ws, size_t ws_size,
                              hipStream_t stream) {
    const float* x = (const float*)d_in[0];
    const int* tok = (const int*)d_in[1];
    int n = in_sizes[1];  // 8192 rows, D = 64

    char* ws = (char*)d_ws;
    size_t o = 0;
    int* offsets = (int*)(ws + o);        o += NTOK * 4;
    int* counts = (int*)(ws + o);         o += NTOK * 4;
    int* order = (int*)(ws + o);          o += ((size_t)n * 4 + 255) & ~255UL;
    float* per_anchor = (float*)(ws + o);
    // every word written before read; no memset dispatch needed

    csr_kernel<<<1, 1024, 0, stream>>>(tok, offsets, counts, order, n);
    lse_kernel<<<(n + 3) / 4, 256, 0, stream>>>(x, tok, offsets, counts, order,
                                                per_anchor, n);
    finalize_kernel<<<1, NTOK, 0, stream>>>(per_anchor, counts, (float*)d_out, n);
}